// Round 2
// baseline (311.920 us; speedup 1.0000x reference)
//
#include <hip/hip_runtime.h>

// ---------------- static config (matches reference) ----------------
// Fine grid only: 2048 x 2048 occupancy bitmap (1 bit/cell) = 512 KB.
// Coarser grids (1024^2, 512^2) are derived: coarse cell = OR of 2x2 / 4x4
// fine cells (floor(p/0.2) == floor(p/0.1)>>1 up to fp rounding; O(1) points
// out of 8M can differ, each shifting a slice count by <=1 -- threshold 1121).
static constexpr int GF = 2048;                       // fine grid dim
static constexpr int WPR = GF / 32;                   // 64 words per fine row
static constexpr unsigned BITMAP_WORDS = (unsigned)GF * GF / 32;  // 131072

// ---------------- scatter: set fine-grid bits ----------------
__global__ void mpc_scatter_bits(const float4* __restrict__ pts4, int npairs,
                                 const float* __restrict__ psz,   // [3][2]
                                 const float* __restrict__ pmin,  // [2]
                                 unsigned int* __restrict__ bm) {
    const float minx = pmin[0], miny = pmin[1];
    const float psx = psz[0], psy = psz[1];   // fine pillar size (0.1, 0.1)

    int i = blockIdx.x * blockDim.x + threadIdx.x;
    const int stride = gridDim.x * blockDim.x;
    for (; i < npairs; i += stride) {
        const float4 q = pts4[i];
#pragma unroll
        for (int k = 0; k < 2; ++k) {
            const float px = (k == 0 ? q.x : q.z) - minx;
            const float py = (k == 0 ? q.y : q.w) - miny;
            int cx = (int)floorf(px / psx);
            int cy = (int)floorf(py / psy);
            cx = min(max(cx, 0), GF - 1);
            cy = min(max(cy, 0), GF - 1);
            const unsigned idx = (unsigned)cy * (unsigned)GF + (unsigned)cx;
            atomicOr(&bm[idx >> 5], 1u << (idx & 31));
        }
    }
}

// ---------------- reduce: per-slice counts for all 3 resolutions ----------------
// block b in [0,112): b<64 -> res0 slice b (32 fine rows);
//                     b<96 -> res1 slice b-64 (64 fine rows, 2x2 OR);
//                     else -> res2 slice b-96 (128 fine rows, 4x4 OR).
__global__ void mpc_reduce_bits(const unsigned int* __restrict__ bm,
                                float* __restrict__ out) {
    const int b = blockIdx.x;
    unsigned int sum = 0;
    const int tid = threadIdx.x;

    if (b < 64) {
        // res0: plain popcount over 32 fine rows = 2048 words
        const unsigned int* base = bm + (size_t)b * 32 * WPR;
        for (int j = tid; j < 32 * WPR; j += blockDim.x)
            sum += __popc(base[j]);
    } else if (b < 96) {
        // res1: 32 coarse rows; each = OR of 2 fine rows, bit-pair collapse
        const int s = b - 64;
        const unsigned int* base = bm + (size_t)s * 64 * WPR;
        for (int j = tid; j < 32 * WPR; j += blockDim.x) {
            const int p = j >> 6;        // coarse row pair within slice
            const int w = j & (WPR - 1); // word within row
            const unsigned r0 = base[(2 * p) * WPR + w];
            const unsigned r1 = base[(2 * p + 1) * WPR + w];
            const unsigned o = r0 | r1;
            sum += __popc((o | (o >> 1)) & 0x55555555u);
        }
    } else {
        // res2: 32 coarse rows; each = OR of 4 fine rows, nibble collapse
        const int s = b - 96;
        const unsigned int* base = bm + (size_t)s * 128 * WPR;
        for (int j = tid; j < 32 * WPR; j += blockDim.x) {
            const int p = j >> 6;
            const int w = j & (WPR - 1);
            const unsigned o = base[(4 * p) * WPR + w] |
                               base[(4 * p + 1) * WPR + w] |
                               base[(4 * p + 2) * WPR + w] |
                               base[(4 * p + 3) * WPR + w];
            sum += __popc((o | (o >> 1) | (o >> 2) | (o >> 3)) & 0x11111111u);
        }
    }

    // wave64 reduce + cross-wave via LDS
#pragma unroll
    for (int o = 32; o > 0; o >>= 1) sum += __shfl_down(sum, o, 64);
    __shared__ unsigned int ssum[4];
    const int wave = tid >> 6, lane = tid & 63;
    if (lane == 0) ssum[wave] = sum;
    __syncthreads();
    if (tid == 0) {
        unsigned int t = 0;
        const int nw = blockDim.x >> 6;
        for (int w = 0; w < nw; ++w) t += ssum[w];
        out[b] = (float)t;
    }
}

extern "C" void kernel_launch(void* const* d_in, const int* in_sizes, int n_in,
                              void* d_out, int out_size, void* d_ws, size_t ws_size,
                              hipStream_t stream) {
    const float4* pts4 = (const float4*)d_in[0];
    const float*  psz  = (const float*)d_in[1];
    const float*  pmn  = (const float*)d_in[2];
    float* out = (float*)d_out;
    const int n = in_sizes[0] / 2;       // number of points (8M, even)
    const int npairs = n / 2;

    unsigned int* bm = (unsigned int*)d_ws;
    hipMemsetAsync(bm, 0, BITMAP_WORDS * sizeof(unsigned int), stream);

    const int threads = 256;
    int blocks = (npairs + threads - 1) / threads;
    if (blocks > 8192) blocks = 8192;

    mpc_scatter_bits<<<blocks, threads, 0, stream>>>(pts4, npairs, psz, pmn, bm);
    mpc_reduce_bits<<<112, 256, 0, stream>>>(bm, out);
}

// Round 3
// 142.532 us; speedup vs baseline: 2.1884x; 2.1884x over previous
//
#include <hip/hip_runtime.h>

// ---------------- static config (matches reference) ----------------
// Fine byte grid only: 2048 x 2048 x 1B = 4 MB (fits one XCD's 4 MiB L2).
// Coarser grids (1024^2, 512^2) are derived in the reduce: coarse cell =
// OR of 2x2 / 4x4 fine cells. floor(p/0.2) == floor(p/0.1)>>1 up to fp
// rounding; O(1) points out of 8M can differ, each shifting one slice
// count by +-1 -- absmax threshold is 1121 (round-1 derivation: absmax 0).
static constexpr int GF = 2048;                     // fine grid dim
static constexpr int WPR = GF / 4;                  // 512 u32 words per fine row
static constexpr int V4PR = GF / 16;                // 128 uint4 per fine row
static constexpr size_t GRID_BYTES = (size_t)GF * GF;  // 4 MiB

typedef float f32x4 __attribute__((ext_vector_type(4)));

// ---------------- scatter: mark fine cells with plain byte stores ----------------
// Idempotent (all racers write 1) -> no atomics needed.
__global__ void mpc_scatter_bytes(const f32x4* __restrict__ pts4, int npairs,
                                  const float* __restrict__ psz,   // [3][2]
                                  const float* __restrict__ pmin,  // [2]
                                  unsigned char* __restrict__ grid) {
    const float minx = pmin[0], miny = pmin[1];
    const float psx = psz[0], psy = psz[1];        // fine pillar size (0.1, 0.1)

    int i = blockIdx.x * blockDim.x + threadIdx.x;
    const int stride = gridDim.x * blockDim.x;
    for (; i < npairs; i += stride) {
        // non-temporal: keep the streaming 64 MB point read out of L2
        const f32x4 q = __builtin_nontemporal_load(&pts4[i]);
#pragma unroll
        for (int k = 0; k < 2; ++k) {
            const float px = (k == 0 ? q.x : q.z) - minx;
            const float py = (k == 0 ? q.y : q.w) - miny;
            int cx = (int)floorf(px / psx);
            int cy = (int)floorf(py / psy);
            cx = min(max(cx, 0), GF - 1);
            cy = min(max(cy, 0), GF - 1);
            grid[(unsigned)cy * (unsigned)GF + (unsigned)cx] = (unsigned char)1;
        }
    }
}

// ---------------- reduce: per-slice counts for all 3 resolutions ----------------
// block b in [0,112): b<64 -> res0 slice b (32 fine rows, popcount of 0/1 bytes)
//                     b<96 -> res1 slice b-64 (64 fine rows, 2x2 byte-OR)
//                     else -> res2 slice b-96 (128 fine rows, 4x4 byte-OR)
// Every branch iterates 4096 uint4 chunks (16 per thread at 256 threads).
__global__ void mpc_reduce_bytes(const uint4* __restrict__ g4,
                                 float* __restrict__ out) {
    const int b = blockIdx.x;
    const int tid = threadIdx.x;
    unsigned int sum = 0;

    if (b < 64) {
        // res0: 32 fine rows = 32*128 uint4; bytes are 0/1 -> popc counts them
        const uint4* base = g4 + (size_t)b * 32 * V4PR;
        for (int j = tid; j < 32 * V4PR; j += blockDim.x) {
            const uint4 v = base[j];
            sum += __popc(v.x) + __popc(v.y) + __popc(v.z) + __popc(v.w);
        }
    } else if (b < 96) {
        // res1: 32 coarse rows/slice; coarse row = OR of 2 fine rows,
        // then collapse column pairs (bytes 0&1 -> one coarse col).
        const int s = b - 64;
        const uint4* base = g4 + (size_t)s * 64 * V4PR;
        for (int j = tid; j < 32 * V4PR; j += blockDim.x) {
            const int cr = j >> 7;           // coarse row in slice
            const int v  = j & (V4PR - 1);   // vec index within row
            const uint4 r0 = base[(size_t)(2 * cr) * V4PR + v];
            const uint4 r1 = base[(size_t)(2 * cr + 1) * V4PR + v];
            unsigned o;
            o = r0.x | r1.x; o |= o >> 8; sum += __popc(o & 0x00010001u);
            o = r0.y | r1.y; o |= o >> 8; sum += __popc(o & 0x00010001u);
            o = r0.z | r1.z; o |= o >> 8; sum += __popc(o & 0x00010001u);
            o = r0.w | r1.w; o |= o >> 8; sum += __popc(o & 0x00010001u);
        }
    } else {
        // res2: 32 coarse rows/slice; coarse row = OR of 4 fine rows,
        // then collapse 4 columns (one word = one coarse col).
        const int s = b - 96;
        const uint4* base = g4 + (size_t)s * 128 * V4PR;
        for (int j = tid; j < 32 * V4PR; j += blockDim.x) {
            const int cr = j >> 7;
            const int v  = j & (V4PR - 1);
            const uint4 a = base[(size_t)(4 * cr) * V4PR + v];
            const uint4 c = base[(size_t)(4 * cr + 1) * V4PR + v];
            const uint4 d = base[(size_t)(4 * cr + 2) * V4PR + v];
            const uint4 e = base[(size_t)(4 * cr + 3) * V4PR + v];
            unsigned o;
            o = a.x | c.x | d.x | e.x; o |= o >> 16; o |= o >> 8; sum += o & 1u;
            o = a.y | c.y | d.y | e.y; o |= o >> 16; o |= o >> 8; sum += o & 1u;
            o = a.z | c.z | d.z | e.z; o |= o >> 16; o |= o >> 8; sum += o & 1u;
            o = a.w | c.w | d.w | e.w; o |= o >> 16; o |= o >> 8; sum += o & 1u;
        }
    }

    // wave64 reduce + cross-wave via LDS
#pragma unroll
    for (int o = 32; o > 0; o >>= 1) sum += __shfl_down(sum, o, 64);
    __shared__ unsigned int ssum[4];
    const int wave = tid >> 6, lane = tid & 63;
    if (lane == 0) ssum[wave] = sum;
    __syncthreads();
    if (tid == 0) {
        unsigned int t = 0;
        const int nw = blockDim.x >> 6;
        for (int w = 0; w < nw; ++w) t += ssum[w];
        out[b] = (float)t;
    }
}

extern "C" void kernel_launch(void* const* d_in, const int* in_sizes, int n_in,
                              void* d_out, int out_size, void* d_ws, size_t ws_size,
                              hipStream_t stream) {
    const f32x4* pts4 = (const f32x4*)d_in[0];
    const float* psz  = (const float*)d_in[1];
    const float* pmn  = (const float*)d_in[2];
    float* out = (float*)d_out;
    const int n = in_sizes[0] / 2;     // number of points (8M, even)
    const int npairs = n / 2;

    unsigned char* grid = (unsigned char*)d_ws;
    hipMemsetAsync(grid, 0, GRID_BYTES, stream);

    const int threads = 256;
    int blocks = (npairs + threads - 1) / threads;
    if (blocks > 8192) blocks = 8192;

    mpc_scatter_bytes<<<blocks, threads, 0, stream>>>(pts4, npairs, psz, pmn, grid);
    mpc_reduce_bytes<<<112, 256, 0, stream>>>((const uint4*)d_ws, out);
}

// Round 4
// 100.322 us; speedup vs baseline: 3.1092x; 1.4207x over previous
//
#include <hip/hip_runtime.h>

// ---------------- static config (matches reference) ----------------
// Fine byte grid only: 2048 x 2048 x 1B = 4 MB. Coarser grids (1024^2,
// 512^2) are derived in the reduce: coarse cell = OR of 2x2 / 4x4 fine
// cells (fp-boundary deltas are O(1) counts vs threshold 1121; measured
// absmax 0 in rounds 1-3).
//
// Scatter is region-partitioned for XCD locality: 4 regions x 512 rows
// (1 MB each). region = blockIdx & 3; with the HW's round-robin
// blockIdx->XCD mapping, region r's blocks land on XCDs {r, r+4}, so each
// XCD L2 keeps only a 1 MB resident slice -> no writeback thrash (round 3:
// whole 4 MB grid in every L2 -> 425 MB HBM writes). Points are re-read
// once per region (4 x 64 MB) but are Infinity-Cache resident.
static constexpr int GF = 2048;                      // fine grid dim
static constexpr int V4PR = GF / 16;                 // 128 uint4 per fine row
static constexpr size_t GRID_BYTES = (size_t)GF * GF;   // 4 MiB
static constexpr int NREG = 4;                       // regions (power of 2)
static constexpr int REG_SHIFT = 9;                  // 2048/4 = 512 rows/region

typedef float f32x4 __attribute__((ext_vector_type(4)));

// ---------------- scatter: region-filtered idempotent byte stores ----------------
__global__ void mpc_scatter_region(const f32x4* __restrict__ pts4, int npairs,
                                   const float* __restrict__ psz,   // [3][2]
                                   const float* __restrict__ pmin,  // [2]
                                   unsigned char* __restrict__ grid) {
    const float minx = pmin[0], miny = pmin[1];
    const float psx = psz[0], psy = psz[1];          // fine pillar size (0.1)

    const int region = blockIdx.x & (NREG - 1);
    const int gblk   = blockIdx.x >> 2;              // block index within group
    const int nblk   = gridDim.x >> 2;               // blocks per group

    int i = gblk * blockDim.x + threadIdx.x;
    const int stride = nblk * blockDim.x;
    for (; i < npairs; i += stride) {
        // nt: keep the streaming point read from evicting the grid region
        const f32x4 q = __builtin_nontemporal_load(&pts4[i]);
#pragma unroll
        for (int k = 0; k < 2; ++k) {
            const float py = (k == 0 ? q.y : q.w) - miny;
            int cy = (int)floorf(py / psy);
            cy = min(max(cy, 0), GF - 1);
            if ((cy >> REG_SHIFT) == region) {
                const float px = (k == 0 ? q.x : q.z) - minx;
                int cx = (int)floorf(px / psx);
                cx = min(max(cx, 0), GF - 1);
                grid[(unsigned)cy * (unsigned)GF + (unsigned)cx] = (unsigned char)1;
            }
        }
    }
}

// ---------------- reduce: per-slice counts for all 3 resolutions ----------------
// block b in [0,112): b<64 -> res0 slice b (32 fine rows, popcount of 0/1 bytes)
//                     b<96 -> res1 slice b-64 (64 fine rows, 2x2 byte-OR)
//                     else -> res2 slice b-96 (128 fine rows, 4x4 byte-OR)
__global__ void mpc_reduce_bytes(const uint4* __restrict__ g4,
                                 float* __restrict__ out) {
    const int b = blockIdx.x;
    const int tid = threadIdx.x;
    unsigned int sum = 0;

    if (b < 64) {
        const uint4* base = g4 + (size_t)b * 32 * V4PR;
        for (int j = tid; j < 32 * V4PR; j += blockDim.x) {
            const uint4 v = base[j];
            sum += __popc(v.x) + __popc(v.y) + __popc(v.z) + __popc(v.w);
        }
    } else if (b < 96) {
        const int s = b - 64;
        const uint4* base = g4 + (size_t)s * 64 * V4PR;
        for (int j = tid; j < 32 * V4PR; j += blockDim.x) {
            const int cr = j >> 7;           // coarse row in slice
            const int v  = j & (V4PR - 1);   // vec index within row
            const uint4 r0 = base[(size_t)(2 * cr) * V4PR + v];
            const uint4 r1 = base[(size_t)(2 * cr + 1) * V4PR + v];
            unsigned o;
            o = r0.x | r1.x; o |= o >> 8; sum += __popc(o & 0x00010001u);
            o = r0.y | r1.y; o |= o >> 8; sum += __popc(o & 0x00010001u);
            o = r0.z | r1.z; o |= o >> 8; sum += __popc(o & 0x00010001u);
            o = r0.w | r1.w; o |= o >> 8; sum += __popc(o & 0x00010001u);
        }
    } else {
        const int s = b - 96;
        const uint4* base = g4 + (size_t)s * 128 * V4PR;
        for (int j = tid; j < 32 * V4PR; j += blockDim.x) {
            const int cr = j >> 7;
            const int v  = j & (V4PR - 1);
            const uint4 a = base[(size_t)(4 * cr) * V4PR + v];
            const uint4 c = base[(size_t)(4 * cr + 1) * V4PR + v];
            const uint4 d = base[(size_t)(4 * cr + 2) * V4PR + v];
            const uint4 e = base[(size_t)(4 * cr + 3) * V4PR + v];
            unsigned o;
            o = a.x | c.x | d.x | e.x; o |= o >> 16; o |= o >> 8; sum += o & 1u;
            o = a.y | c.y | d.y | e.y; o |= o >> 16; o |= o >> 8; sum += o & 1u;
            o = a.z | c.z | d.z | e.z; o |= o >> 16; o |= o >> 8; sum += o & 1u;
            o = a.w | c.w | d.w | e.w; o |= o >> 16; o |= o >> 8; sum += o & 1u;
        }
    }

#pragma unroll
    for (int o = 32; o > 0; o >>= 1) sum += __shfl_down(sum, o, 64);
    __shared__ unsigned int ssum[4];
    const int wave = tid >> 6, lane = tid & 63;
    if (lane == 0) ssum[wave] = sum;
    __syncthreads();
    if (tid == 0) {
        unsigned int t = 0;
        const int nw = blockDim.x >> 6;
        for (int w = 0; w < nw; ++w) t += ssum[w];
        out[b] = (float)t;
    }
}

extern "C" void kernel_launch(void* const* d_in, const int* in_sizes, int n_in,
                              void* d_out, int out_size, void* d_ws, size_t ws_size,
                              hipStream_t stream) {
    const f32x4* pts4 = (const f32x4*)d_in[0];
    const float* psz  = (const float*)d_in[1];
    const float* pmn  = (const float*)d_in[2];
    float* out = (float*)d_out;
    const int n = in_sizes[0] / 2;     // number of points (8M, even)
    const int npairs = n / 2;

    unsigned char* grid = (unsigned char*)d_ws;
    hipMemsetAsync(grid, 0, GRID_BYTES, stream);

    const int threads = 256;
    const int blocks = 2048;           // multiple of 8: balanced XCD spread

    mpc_scatter_region<<<blocks, threads, 0, stream>>>(pts4, npairs, psz, pmn, grid);
    mpc_reduce_bytes<<<112, 256, 0, stream>>>((const uint4*)d_ws, out);
}

// Round 5
// 91.371 us; speedup vs baseline: 3.4138x; 1.0980x over previous
//
#include <hip/hip_runtime.h>

// ---------------- static config (matches reference) ----------------
// Fine byte grid only: 2048 x 2048 x 1B = 4 MB. Coarser grids (1024^2,
// 512^2) are derived in the reduce: coarse cell = OR of 2x2 / 4x4 fine
// cells. Reciprocal-multiply instead of fp divide shifts floor() only for
// boundary-adjacent points (O(few) of 8M, each +-1 on one slice count;
// threshold 1121, measured absmax 0 through round 4 with derivation).
//
// Scatter is region-partitioned for XCD locality: NREG=2 regions x 1024
// rows (2 MB each). region = blockIdx & 1; round-robin blockIdx->XCD
// mapping lands region r on XCDs {r, r+2, r+4, r+6}; each XCD L2 keeps a
// 2 MB resident slice + 2 MB headroom for the nt point stream.
// (Round 3: whole 4 MB grid resident -> 425 MB HBM writeback thrash.
//  Round 4: NREG=4 -> 8.6 MB writes but 4 passes = 256 MB point re-reads.)
static constexpr int GF = 2048;                      // fine grid dim
static constexpr int V4PR = GF / 16;                 // 128 uint4 per fine row
static constexpr size_t GRID_BYTES = (size_t)GF * GF;   // 4 MiB
static constexpr int NREG = 2;                       // regions (power of 2)
static constexpr int REG_SHIFT = 10;                 // 2048/2 = 1024 rows/region

typedef float f32x4 __attribute__((ext_vector_type(4)));

// ---------------- scatter: region-filtered idempotent byte stores ----------------
__global__ void mpc_scatter_region(const f32x4* __restrict__ pts4, int npairs,
                                   const float* __restrict__ psz,   // [3][2]
                                   const float* __restrict__ pmin,  // [2]
                                   unsigned char* __restrict__ grid) {
    const float minx = pmin[0], miny = pmin[1];
    const float rx = 1.0f / psz[0], ry = 1.0f / psz[1];  // 1/0.1 (once per thread)

    const int region = blockIdx.x & (NREG - 1);
    const int gblk   = blockIdx.x >> 1;              // block index within group
    const int nblk   = gridDim.x >> 1;               // blocks per group
    const int tpg    = nblk * blockDim.x;            // threads per group

    auto process = [&](const f32x4& q) {
#pragma unroll
        for (int k = 0; k < 2; ++k) {
            const float py = (k == 0 ? q.y : q.w) - miny;
            int cy = __float2int_rd(py * ry);
            cy = min(max(cy, 0), GF - 1);
            if ((cy >> REG_SHIFT) == region) {
                const float px = (k == 0 ? q.x : q.z) - minx;
                int cx = __float2int_rd(px * rx);
                cx = min(max(cx, 0), GF - 1);
                grid[(unsigned)cy * (unsigned)GF + (unsigned)cx] = (unsigned char)1;
            }
        }
    };

    // 2-way unroll: two independent nt loads in flight per iteration
    int i = gblk * blockDim.x + threadIdx.x;
    for (; i < npairs; i += 2 * tpg) {
        const f32x4 q0 = __builtin_nontemporal_load(&pts4[i]);
        const int i1 = i + tpg;
        if (i1 < npairs) {
            const f32x4 q1 = __builtin_nontemporal_load(&pts4[i1]);
            process(q0);
            process(q1);
        } else {
            process(q0);
        }
    }
}

// ---------------- reduce: per-slice counts for all 3 resolutions ----------------
// block b in [0,112): b<64 -> res0 slice b (32 fine rows, popcount of 0/1 bytes)
//                     b<96 -> res1 slice b-64 (64 fine rows, 2x2 byte-OR)
//                     else -> res2 slice b-96 (128 fine rows, 4x4 byte-OR)
__global__ void mpc_reduce_bytes(const uint4* __restrict__ g4,
                                 float* __restrict__ out) {
    const int b = blockIdx.x;
    const int tid = threadIdx.x;
    unsigned int sum = 0;

    if (b < 64) {
        const uint4* base = g4 + (size_t)b * 32 * V4PR;
        for (int j = tid; j < 32 * V4PR; j += blockDim.x) {
            const uint4 v = base[j];
            sum += __popc(v.x) + __popc(v.y) + __popc(v.z) + __popc(v.w);
        }
    } else if (b < 96) {
        const int s = b - 64;
        const uint4* base = g4 + (size_t)s * 64 * V4PR;
        for (int j = tid; j < 32 * V4PR; j += blockDim.x) {
            const int cr = j >> 7;           // coarse row in slice
            const int v  = j & (V4PR - 1);   // vec index within row
            const uint4 r0 = base[(size_t)(2 * cr) * V4PR + v];
            const uint4 r1 = base[(size_t)(2 * cr + 1) * V4PR + v];
            unsigned o;
            o = r0.x | r1.x; o |= o >> 8; sum += __popc(o & 0x00010001u);
            o = r0.y | r1.y; o |= o >> 8; sum += __popc(o & 0x00010001u);
            o = r0.z | r1.z; o |= o >> 8; sum += __popc(o & 0x00010001u);
            o = r0.w | r1.w; o |= o >> 8; sum += __popc(o & 0x00010001u);
        }
    } else {
        const int s = b - 96;
        const uint4* base = g4 + (size_t)s * 128 * V4PR;
        for (int j = tid; j < 32 * V4PR; j += blockDim.x) {
            const int cr = j >> 7;
            const int v  = j & (V4PR - 1);
            const uint4 a = base[(size_t)(4 * cr) * V4PR + v];
            const uint4 c = base[(size_t)(4 * cr + 1) * V4PR + v];
            const uint4 d = base[(size_t)(4 * cr + 2) * V4PR + v];
            const uint4 e = base[(size_t)(4 * cr + 3) * V4PR + v];
            unsigned o;
            o = a.x | c.x | d.x | e.x; o |= o >> 16; o |= o >> 8; sum += o & 1u;
            o = a.y | c.y | d.y | e.y; o |= o >> 16; o |= o >> 8; sum += o & 1u;
            o = a.z | c.z | d.z | e.z; o |= o >> 16; o |= o >> 8; sum += o & 1u;
            o = a.w | c.w | d.w | e.w; o |= o >> 16; o |= o >> 8; sum += o & 1u;
        }
    }

#pragma unroll
    for (int o = 32; o > 0; o >>= 1) sum += __shfl_down(sum, o, 64);
    __shared__ unsigned int ssum[4];
    const int wave = tid >> 6, lane = tid & 63;
    if (lane == 0) ssum[wave] = sum;
    __syncthreads();
    if (tid == 0) {
        unsigned int t = 0;
        const int nw = blockDim.x >> 6;
        for (int w = 0; w < nw; ++w) t += ssum[w];
        out[b] = (float)t;
    }
}

extern "C" void kernel_launch(void* const* d_in, const int* in_sizes, int n_in,
                              void* d_out, int out_size, void* d_ws, size_t ws_size,
                              hipStream_t stream) {
    const f32x4* pts4 = (const f32x4*)d_in[0];
    const float* psz  = (const float*)d_in[1];
    const float* pmn  = (const float*)d_in[2];
    float* out = (float*)d_out;
    const int n = in_sizes[0] / 2;     // number of points (8M, even)
    const int npairs = n / 2;

    unsigned char* grid = (unsigned char*)d_ws;
    hipMemsetAsync(grid, 0, GRID_BYTES, stream);

    const int threads = 256;
    const int blocks = 2048;           // multiple of 8: balanced XCD spread

    mpc_scatter_region<<<blocks, threads, 0, stream>>>(pts4, npairs, psz, pmn, grid);
    mpc_reduce_bytes<<<112, 256, 0, stream>>>((const uint4*)d_ws, out);
}